// Round 11
// baseline (33.621 us; speedup 1.0000x reference)
//
#include <hip/hip_runtime.h>
#include <math.h>

#define BSZ 512
#define DSZ 512
#define MARGIN 0.4f
#define ALPHA 1.0f
#define NBLK 256   // 2 anchors per block

typedef unsigned int u32;

static __device__ __forceinline__ u32 pack_bf16x2(float a, float b) {
    // rne bf16; lo16 = a, hi16 = b
    u32 ua = __float_as_uint(a);
    ua = (ua + 0x7fffu + ((ua >> 16) & 1u)) >> 16;
    u32 ub = __float_as_uint(b);
    ub = (ub + 0x7fffu + ((ub >> 16) & 1u)) & 0xffff0000u;
    return ua | ub;
}

// ---- K0: exact f32 norms + normalize + bf16 + dual-layout write ------
// 64 blocks x 512 threads; wave w owns row r = 8*bid + w.
// ENR[r][k] row-major bf16 (anchor operands, coalesced uint4 writes);
// PT4[k4][j] uint2 = 4 bf16 (column stream, 8B scattered writes).
__global__ __launch_bounds__(512) void rll_prep(const float* __restrict__ emb,
                                                u32* __restrict__ enr,
                                                uint2* __restrict__ pt4,
                                                int* __restrict__ counter) {
    const int w = threadIdx.x >> 6, l = threadIdx.x & 63;
    const int r = blockIdx.x * 8 + w;
    if (blockIdx.x == 0 && threadIdx.x == 0) counter[0] = 0;   // re-arm per replay
    const float4* src = (const float4*)(emb + (size_t)r * DSZ);
    float4 v0 = src[l * 2];
    float4 v1 = src[l * 2 + 1];
    float ss = v0.x * v0.x + v0.y * v0.y + v0.z * v0.z + v0.w * v0.w
             + v1.x * v1.x + v1.y * v1.y + v1.z * v1.z + v1.w * v1.w;
    #pragma unroll
    for (int off = 32; off > 0; off >>= 1) ss += __shfl_xor(ss, off);
    const float inv = 1.0f / fmaxf(sqrtf(ss), 1e-12f);
    v0.x *= inv; v0.y *= inv; v0.z *= inv; v0.w *= inv;
    v1.x *= inv; v1.y *= inv; v1.z *= inv; v1.w *= inv;
    const u32 p0 = pack_bf16x2(v0.x, v0.y);
    const u32 p1 = pack_bf16x2(v0.z, v0.w);
    const u32 p2 = pack_bf16x2(v1.x, v1.y);
    const u32 p3 = pack_bf16x2(v1.z, v1.w);
    // row-major: uints 4l..4l+3 of row r (16B/lane, coalesced)
    *(uint4*)&enr[(size_t)r * 256 + l * 4] = make_uint4(p0, p1, p2, p3);
    // transposed: k4 = 2l and 2l+1, column j = r (8B scatter)
    pt4[(size_t)(2 * l) * BSZ + r]     = make_uint2(p0, p1);
    pt4[(size_t)(2 * l + 1) * BSZ + r] = make_uint2(p2, p3);
}

// ---- K1: bf16 dots (coalesced) + dist-in-LDS + count + final reduce --
// 256 blocks x 512 threads (8 waves). Block b owns anchors {2b, 2b+1};
// thread tid owns column j = tid. Rows pre-normalized: d2 = 2 - 2*dot.
__global__ __launch_bounds__(512) void rll_fused(const u32* __restrict__ enr,
                                                 const uint2* __restrict__ pt4,
                                                 const int* __restrict__ labels,
                                                 float* __restrict__ partial,
                                                 int* __restrict__ counter,
                                                 float* __restrict__ out) {
    __shared__ float dsh[2][BSZ];
    __shared__ int   lsh[BSZ];
    __shared__ int   pos[2][128];
    __shared__ int   np[2];
    __shared__ float wacc[8];
    __shared__ bool  last;

    const int tid = threadIdx.x;          // column j
    const int w = tid >> 6, l = tid & 63;
    const int i0 = blockIdx.x * 2, i1 = i0 + 1;

    lsh[tid] = labels[tid];
    if (tid < 2) np[tid] = 0;
    __syncthreads();

    const int l0 = lsh[i0], l1 = lsh[i1];
    if (lsh[tid] == l0 && tid != i0) pos[0][atomicAdd(&np[0], 1) & 127] = tid;
    if (lsh[tid] == l1 && tid != i1) pos[1][atomicAdd(&np[1], 1) & 127] = tid;

    // ---- dot products ----
    const uint2* __restrict__ a0p = (const uint2*)(enr + (size_t)i0 * 256);
    const uint2* __restrict__ a1p = (const uint2*)(enr + (size_t)i1 * 256);
    float acc0 = 0.f, acc1 = 0.f;
    #pragma unroll 8
    for (int k4 = 0; k4 < 128; ++k4) {
        const uint2 c  = pt4[(size_t)k4 * BSZ + tid];   // coalesced 8B/lane
        const uint2 a0 = a0p[k4];                       // wave-uniform
        const uint2 a1 = a1p[k4];
        const float c0 = __uint_as_float(c.x << 16);
        const float c1 = __uint_as_float(c.x & 0xffff0000u);
        const float c2 = __uint_as_float(c.y << 16);
        const float c3 = __uint_as_float(c.y & 0xffff0000u);
        const float a00 = __uint_as_float(a0.x << 16);
        const float a01 = __uint_as_float(a0.x & 0xffff0000u);
        const float a02 = __uint_as_float(a0.y << 16);
        const float a03 = __uint_as_float(a0.y & 0xffff0000u);
        const float a10 = __uint_as_float(a1.x << 16);
        const float a11 = __uint_as_float(a1.x & 0xffff0000u);
        const float a12 = __uint_as_float(a1.y << 16);
        const float a13 = __uint_as_float(a1.y & 0xffff0000u);
        acc0 = fmaf(c3, a03, fmaf(c2, a02, fmaf(c1, a01, fmaf(c0, a00, acc0))));
        acc1 = fmaf(c3, a13, fmaf(c2, a12, fmaf(c1, a11, fmaf(c0, a10, acc1))));
    }
    dsh[0][tid] = sqrtf(fmaxf(2.0f - 2.0f * acc0, 0.0f));
    dsh[1][tid] = sqrtf(fmaxf(2.0f - 2.0f * acc1, 0.0f));
    __syncthreads();

    // ---- counting: anchor s = w&1; 4 waves stride each positive list ----
    const int s = w & 1;
    const int li = s ? l1 : l0;
    const int n = min(np[s], 128);
    float accl = 0.f;
    for (int p = (w >> 1); p < n; p += 4) {
        const int jj = pos[s][p];
        const float thr = dsh[s][jj] + MARGIN;
        int cnt = 0;
        #pragma unroll
        for (int q = 0; q < 8; ++q) {
            const int k = l + q * 64;
            cnt += (lsh[k] != li && dsh[s][k] < thr) ? 1 : 0;
        }
        #pragma unroll
        for (int off = 32; off > 0; off >>= 1) cnt += __shfl_down(cnt, off);
        if (l == 0 && cnt > 0) accl += log1pf((float)cnt);
    }
    if (l == 0) wacc[w] = accl;
    __syncthreads();

    // ---- per-block partial + last-block final reduce ----
    if (tid == 0) {
        float t = 0.f;
        #pragma unroll
        for (int q = 0; q < 8; ++q) t += wacc[q];
        partial[blockIdx.x] = t;
        __threadfence();
        const int old = atomicAdd(counter, 1);
        last = (old == NBLK - 1);
    }
    __syncthreads();
    if (last) {
        __threadfence();
        if (tid < 64) {
            volatile const float* vp = (volatile const float*)partial;
            float t = 0.f;
            #pragma unroll
            for (int q = 0; q < NBLK / 64; ++q) t += vp[tid + q * 64];
            #pragma unroll
            for (int off = 32; off > 0; off >>= 1) t += __shfl_down(t, off);
            if (tid == 0) out[0] = t * (ALPHA / (512.0f + 1e-8f));
        }
    }
}

extern "C" void kernel_launch(void* const* d_in, const int* in_sizes, int n_in,
                              void* d_out, int out_size, void* d_ws, size_t ws_size,
                              hipStream_t stream) {
    const float* emb    = (const float*)d_in[0];
    const int*   labels = (const int*)d_in[1];
    float* out = (float*)d_out;

    // ws: ENR (512*256 u32) | PT4 (128*512 uint2) | partial (256 f32) | counter
    u32*   enr     = (u32*)d_ws;
    uint2* pt4     = (uint2*)(enr + (size_t)BSZ * 256);
    float* partial = (float*)(pt4 + (size_t)128 * BSZ);
    int*   counter = (int*)(partial + NBLK);

    rll_prep<<<64, 512, 0, stream>>>(emb, enr, pt4, counter);
    rll_fused<<<NBLK, 512, 0, stream>>>(enr, pt4, labels, partial, counter, out);
}

// Round 12
// 25.718 us; speedup vs baseline: 1.3073x; 1.3073x over previous
//
#include <hip/hip_runtime.h>
#include <math.h>

#define BSZ 512
#define DSZ 512
#define MARGIN 0.4f
#define ALPHA 1.0f

typedef unsigned int u32;
typedef __attribute__((ext_vector_type(8))) short bf16x8;
typedef __attribute__((ext_vector_type(4))) float f32x4;

static __device__ __forceinline__ u32 pack_bf16x2(float a, float b) {
    u32 ua = __float_as_uint(a);
    ua = (ua + 0x7fffu + ((ua >> 16) & 1u)) >> 16;
    u32 ub = __float_as_uint(b);
    ub = (ub + 0x7fffu + ((ub >> 16) & 1u)) & 0xffff0000u;
    return ua | ub;
}

// ---- K0: exact f32 norms + normalize + bf16 row-major (coalesced) ----
// 64 blocks x 512 threads; wave w owns row r = 8*bid + w.
__global__ __launch_bounds__(512) void rll_prep(const float* __restrict__ emb,
                                                u32* __restrict__ enr) {
    const int w = threadIdx.x >> 6, l = threadIdx.x & 63;
    const int r = blockIdx.x * 8 + w;
    const float4* src = (const float4*)(emb + (size_t)r * DSZ);
    float4 v0 = src[l * 2];
    float4 v1 = src[l * 2 + 1];
    float ss = v0.x * v0.x + v0.y * v0.y + v0.z * v0.z + v0.w * v0.w
             + v1.x * v1.x + v1.y * v1.y + v1.z * v1.z + v1.w * v1.w;
    #pragma unroll
    for (int off = 32; off > 0; off >>= 1) ss += __shfl_xor(ss, off);
    const float inv = 1.0f / fmaxf(sqrtf(ss), 1e-12f);
    v0.x *= inv; v0.y *= inv; v0.z *= inv; v0.w *= inv;
    v1.x *= inv; v1.y *= inv; v1.z *= inv; v1.w *= inv;
    *(uint4*)&enr[(size_t)r * 256 + l * 4] =
        make_uint4(pack_bf16x2(v0.x, v0.y), pack_bf16x2(v0.z, v0.w),
                   pack_bf16x2(v1.x, v1.y), pack_bf16x2(v1.z, v1.w));
}

// ---- K1: LDS-free MFMA dist tile ------------------------------------
// 256 blocks (16x16 of 32x32 tiles) x 256 threads (4 waves, 2x2 quadrants
// of 16x16 frags). Fragments straight from L2-resident ENR; per wave:
// 16 A-loads + 16 B-loads + 16 MFMA. dist = sqrt(max(2-2*dot,0)).
// Fragment & D layout identical to the R7/R8-verified kernels.
__global__ __launch_bounds__(256) void rll_dist(const u32* __restrict__ enr,
                                                float* __restrict__ dist) {
    const int tid = threadIdx.x;
    const int w = tid >> 6, l = tid & 63;
    const int wr = w >> 1, wc = w & 1;
    const int brow = blockIdx.y * 32, bcol = blockIdx.x * 32;
    const int fr = l & 15;
    const int fk = (l >> 4) * 4;            // u32 offset within 32-elem chunk

    const u32* arow = enr + (size_t)(brow + wr * 16 + fr) * 256 + fk;
    const u32* brow_ = enr + (size_t)(bcol + wc * 16 + fr) * 256 + fk;

    bf16x8 afrag[16];
    #pragma unroll
    for (int kc = 0; kc < 16; ++kc)
        afrag[kc] = *(const bf16x8*)(arow + kc * 16);

    f32x4 acc = {0.f, 0.f, 0.f, 0.f};
    #pragma unroll
    for (int kc = 0; kc < 16; ++kc) {
        const bf16x8 b = *(const bf16x8*)(brow_ + kc * 16);
        acc = __builtin_amdgcn_mfma_f32_16x16x32_bf16(afrag[kc], b, acc, 0, 0, 0);
    }

    // D: col = l&15, row = (l>>4)*4 + r  (R7-verified)
    const int col = bcol + wc * 16 + fr;
    const int rowbase = brow + wr * 16 + ((l >> 4) << 2);
    #pragma unroll
    for (int r = 0; r < 4; ++r)
        dist[(size_t)(rowbase + r) * BSZ + col] =
            sqrtf(fmaxf(2.0f - 2.0f * acc[r], 0.0f));
}

// ---- K2: ranked-list counting, per-anchor partial (no atomics) -------
// 512 blocks x 256 threads (4 waves).
__global__ __launch_bounds__(256) void rll_count(const float* __restrict__ dist,
                                                 const int* __restrict__ labels,
                                                 float* __restrict__ partial) {
    __shared__ float dsh[BSZ];
    __shared__ int   lsh[BSZ];
    __shared__ int   pos[128];
    __shared__ int   npos;
    __shared__ float wsum[4];
    const int i = blockIdx.x;
    const int tid = threadIdx.x;
    if (tid == 0) npos = 0;
    if (tid < 128) {
        *(float4*)&dsh[tid * 4] = ((const float4*)(dist + (size_t)i * BSZ))[tid];
        *(int4*)&lsh[tid * 4]   = ((const int4*)labels)[tid];
    }
    __syncthreads();
    const int li = lsh[i];
    for (int j = tid; j < BSZ; j += 256) {
        if (j != i && lsh[j] == li) {
            const int idx = atomicAdd(&npos, 1);
            if (idx < 128) pos[idx] = j;
        }
    }
    if (tid < 4) wsum[tid] = 0.f;
    __syncthreads();
    const int wave = tid >> 6, lane = tid & 63;
    const int np = min(npos, 128);
    float acc = 0.f;
    for (int p = wave; p < np; p += 4) {
        const int j = pos[p];
        const float thr = dsh[j] + MARGIN;
        int cnt = 0;
        #pragma unroll
        for (int q = 0; q < 8; ++q) {
            const int k = lane + q * 64;
            cnt += (lsh[k] != li && dsh[k] < thr) ? 1 : 0;
        }
        #pragma unroll
        for (int off = 32; off > 0; off >>= 1) cnt += __shfl_down(cnt, off);
        if (lane == 0 && cnt > 0) acc += log1pf((float)cnt);
    }
    if (lane == 0) wsum[wave] = acc;
    __syncthreads();
    if (tid == 0)
        partial[i] = wsum[0] + wsum[1] + wsum[2] + wsum[3];  // unconditional
}

// ---- K3: 512-partial reduce -> out[0] --------------------------------
__global__ __launch_bounds__(64) void rll_reduce(const float* __restrict__ partial,
                                                 float* __restrict__ out) {
    const int lane = threadIdx.x;
    float s = 0.f;
    #pragma unroll
    for (int q = 0; q < BSZ / 64; ++q) s += partial[lane + q * 64];
    #pragma unroll
    for (int off = 32; off > 0; off >>= 1) s += __shfl_down(s, off);
    if (lane == 0) out[0] = s * (ALPHA / (512.0f + 1e-8f));
}

extern "C" void kernel_launch(void* const* d_in, const int* in_sizes, int n_in,
                              void* d_out, int out_size, void* d_ws, size_t ws_size,
                              hipStream_t stream) {
    const float* emb    = (const float*)d_in[0];
    const int*   labels = (const int*)d_in[1];
    float* out = (float*)d_out;

    // ws: ENR (512*256 u32) | dist (512*512 f32) | partial (512 f32)
    u32*   enr     = (u32*)d_ws;
    float* dist    = (float*)(enr + (size_t)BSZ * 256);
    float* partial = dist + (size_t)BSZ * BSZ;

    rll_prep<<<64, 512, 0, stream>>>(emb, enr);
    rll_dist<<<dim3(16, 16), 256, 0, stream>>>(enr, dist);
    rll_count<<<BSZ, 256, 0, stream>>>(dist, labels, partial);
    rll_reduce<<<1, 64, 0, stream>>>(partial, out);
}